// Round 1
// baseline (838.302 us; speedup 1.0000x reference)
//
#include <hip/hip_runtime.h>

#define NN 100000
#define NE 1600000
#define D  64

// ---------------- degree ----------------
__global__ void k_init_deg(float* __restrict__ deg) {
    int i = blockIdx.x * blockDim.x + threadIdx.x;
    if (i < NN) deg[i] = 1.0f;   // self-loop contributes 1 to every node's degree
}

__global__ void k_edge_deg(const int* __restrict__ dst, float* __restrict__ deg) {
    int e = blockIdx.x * blockDim.x + threadIdx.x;
    if (e < NE) atomicAdd(&deg[dst[e]], 1.0f);
}

// ---------------- fused GEMMs + out init ----------------
// One wave per node. Lane j computes h[i][j] = sum_k x[i][k]*Wg[k][j] via
// wave-broadcast of the x row (each lane holds x[i][lane], __shfl broadcasts
// x[i][k]). W matrices staged in LDS (2 x 16 KB). out is initialized with
// self-loop term + pos branch + both biases, so the scatter kernel is pure
// atomic accumulation afterwards.
__global__ __launch_bounds__(256) void k_gemm(
    const float* __restrict__ x, const float* __restrict__ pos,
    const float* __restrict__ Wg, const float* __restrict__ bg,
    const float* __restrict__ Wp, const float* __restrict__ bp,
    const float* __restrict__ deg, float* __restrict__ dinv,
    float* __restrict__ h, float* __restrict__ out)
{
    __shared__ float sWg[D * D];
    __shared__ float sWp[D * D];
    int t = threadIdx.x;
    for (int k = t; k < D * D; k += 256) { sWg[k] = Wg[k]; sWp[k] = Wp[k]; }
    __syncthreads();

    int wave = t >> 6;
    int lane = t & 63;
    int i = blockIdx.x * 4 + wave;
    if (i >= NN) return;

    float xv = x[(long)i * D + lane];
    float pv = pos[(long)i * D + lane];
    float acc_h = 0.f, acc_p = 0.f;
#pragma unroll
    for (int k = 0; k < D; ++k) {
        float a = __shfl(xv, k);
        float b = __shfl(pv, k);
        acc_h = fmaf(a, sWg[k * D + lane], acc_h);
        acc_p = fmaf(b, sWp[k * D + lane], acc_p);
    }
    float di = rsqrtf(deg[i]);   // deg >= 1 always (self-loop), no zero guard needed
    if (lane == 0) dinv[i] = di;
    h[(long)i * D + lane] = acc_h;
    out[(long)i * D + lane] = acc_h * di * di + bg[lane] + acc_p + bp[lane];
}

// ---------------- edge scatter ----------------
// One wave per edge; lane j handles feature j. Gather h[src] (L3-resident),
// scale by dinv[src]*dinv[dst], atomicAdd into out[dst].
__global__ __launch_bounds__(256) void k_scatter(
    const int* __restrict__ src, const int* __restrict__ dst,
    const float* __restrict__ dinv, const float* __restrict__ h,
    float* __restrict__ out)
{
    int wid = (int)((blockIdx.x * (unsigned)blockDim.x + threadIdx.x) >> 6);
    int lane = threadIdx.x & 63;
    if (wid >= NE) return;
    int s = src[wid];
    int d = dst[wid];
    float norm = dinv[s] * dinv[d];
    float v = h[(long)s * D + lane] * norm;
    atomicAdd(&out[(long)d * D + lane], v);
}

extern "C" void kernel_launch(void* const* d_in, const int* in_sizes, int n_in,
                              void* d_out, int out_size, void* d_ws, size_t ws_size,
                              hipStream_t stream) {
    const float* x   = (const float*)d_in[0];
    const int*   ei  = (const int*)d_in[1];   // [2, NE] int32
    const float* pos = (const float*)d_in[2];
    const float* Wg  = (const float*)d_in[3];
    const float* bg  = (const float*)d_in[4];
    const float* Wp  = (const float*)d_in[5];
    const float* bp  = (const float*)d_in[6];
    float* out = (float*)d_out;

    // workspace layout: deg[NN] | dinv[NN] | h[NN*D]  (~26.4 MB)
    float* deg  = (float*)d_ws;
    float* dinv = deg + NN;
    float* h    = dinv + NN;

    const int* src = ei;
    const int* dst = ei + NE;

    hipLaunchKernelGGL(k_init_deg, dim3((NN + 255) / 256), dim3(256), 0, stream, deg);
    hipLaunchKernelGGL(k_edge_deg, dim3((NE + 255) / 256), dim3(256), 0, stream, dst, deg);
    hipLaunchKernelGGL(k_gemm, dim3((NN + 3) / 4), dim3(256), 0, stream,
                       x, pos, Wg, bg, Wp, bp, deg, dinv, h, out);
    hipLaunchKernelGGL(k_scatter, dim3((NE + 3) / 4), dim3(256), 0, stream,
                       src, dst, dinv, h, out);
}

// Round 2
// 572.934 us; speedup vs baseline: 1.4632x; 1.4632x over previous
//
#include <hip/hip_runtime.h>

#define NN 100000
#define NE 1600000
#define D  64

// ---------------- CSR build ----------------
__global__ void k_zero(int* __restrict__ cnt, int* __restrict__ total) {
    int i = blockIdx.x * blockDim.x + threadIdx.x;
    if (i < NN) cnt[i] = 0;
    if (i == 0) *total = 0;
}

__global__ void k_count(const int* __restrict__ dst, int* __restrict__ cnt) {
    int e = blockIdx.x * blockDim.x + threadIdx.x;
    if (e < NE) atomicAdd(&cnt[dst[e]], 1);
}

// Per-block (256-node) inclusive scan + one atomicAdd per block on the global
// cursor; bucket order across blocks is arbitrary, which is fine (each node's
// bucket is contiguous; out rows are written by node id regardless).
__global__ __launch_bounds__(256) void k_alloc(
    const int* __restrict__ cnt, float* __restrict__ dinv,
    int* __restrict__ row_start, int* __restrict__ wpos, int* __restrict__ total)
{
    __shared__ int s[256];
    __shared__ int sbase;
    int t = threadIdx.x;
    int i = blockIdx.x * 256 + t;
    int c = (i < NN) ? cnt[i] : 0;
    s[t] = c;
    __syncthreads();
    for (int off = 1; off < 256; off <<= 1) {
        int v = s[t];
        int u = (t >= off) ? s[t - off] : 0;
        __syncthreads();
        s[t] = v + u;
        __syncthreads();
    }
    if (t == 255) sbase = atomicAdd(total, s[255]);
    __syncthreads();
    if (i < NN) {
        int rs = sbase + s[t] - c;   // exclusive prefix + block base
        row_start[i] = rs;
        wpos[i] = rs;
        dinv[i] = rsqrtf((float)(c + 1));   // +1: self-loop
    }
}

__global__ void k_fill(const int* __restrict__ src, const int* __restrict__ dst,
                       int* __restrict__ wpos, int* __restrict__ bucket) {
    int e = blockIdx.x * blockDim.x + threadIdx.x;
    if (e < NE) {
        int d = dst[e];
        int p = atomicAdd(&wpos[d], 1);
        bucket[p] = src[e];
    }
}

// ---------------- fused GEMMs ----------------
// Wave per node (4 nodes per wave, looped). g[i] = (x[i]@Wg)*dinv[i];
// out[i] = pos[i]@Wp + bp + bg  (base; gather adds the aggregation term).
__global__ __launch_bounds__(256) void k_gemm(
    const float* __restrict__ x, const float* __restrict__ pos,
    const float* __restrict__ Wg, const float* __restrict__ bg,
    const float* __restrict__ Wp, const float* __restrict__ bp,
    const float* __restrict__ dinv,
    float* __restrict__ g, float* __restrict__ out)
{
    __shared__ float sWg[D * D];
    __shared__ float sWp[D * D];
    int t = threadIdx.x;
    for (int k = t; k < D * D; k += 256) { sWg[k] = Wg[k]; sWp[k] = Wp[k]; }
    __syncthreads();

    int wave = t >> 6;
    int lane = t & 63;
    float bsum = bg[lane] + bp[lane];
    int i0 = blockIdx.x * 16 + wave * 4;
    for (int n = 0; n < 4; ++n) {
        int i = i0 + n;
        if (i >= NN) break;
        float xv = x[(long)i * D + lane];
        float pv = pos[(long)i * D + lane];
        float ah = 0.f, ap = 0.f;
#pragma unroll
        for (int k = 0; k < D; ++k) {
            ah = fmaf(__shfl(xv, k), sWg[k * D + lane], ah);
            ap = fmaf(__shfl(pv, k), sWp[k * D + lane], ap);
        }
        float di = dinv[i];
        g[(long)i * D + lane]   = ah * di;
        out[(long)i * D + lane] = ap + bsum;
    }
}

// ---------------- gather (no atomics) ----------------
// Wave per dst node; lane = feature. acc = g[self] + sum over bucket of
// g[src]; out += acc * dinv[dst].
__global__ __launch_bounds__(256) void k_gather(
    const int* __restrict__ row_start, const int* __restrict__ cnt,
    const int* __restrict__ bucket, const float* __restrict__ dinv,
    const float* __restrict__ g, float* __restrict__ out)
{
    int wid = (blockIdx.x << 2) + (threadIdx.x >> 6);
    int lane = threadIdx.x & 63;
    if (wid >= NN) return;

    float acc = g[(long)wid * D + lane];   // self-loop term
    int rs = row_start[wid];
    int n  = cnt[wid];
    for (int b = 0; b < n; b += 64) {
        int m = n - b; if (m > 64) m = 64;
        int bl = (lane < m) ? bucket[rs + b + lane] : 0;
        for (int j = 0; j < m; ++j) {
            int s = __shfl(bl, j);
            acc += g[(long)s * D + lane];
        }
    }
    out[(long)wid * D + lane] += acc * dinv[wid];
}

extern "C" void kernel_launch(void* const* d_in, const int* in_sizes, int n_in,
                              void* d_out, int out_size, void* d_ws, size_t ws_size,
                              hipStream_t stream) {
    const float* x   = (const float*)d_in[0];
    const int*   ei  = (const int*)d_in[1];   // [2, NE] int32
    const float* pos = (const float*)d_in[2];
    const float* Wg  = (const float*)d_in[3];
    const float* bg  = (const float*)d_in[4];
    const float* Wp  = (const float*)d_in[5];
    const float* bp  = (const float*)d_in[6];
    float* out = (float*)d_out;

    const int* src = ei;
    const int* dst = ei + NE;

    // ws layout: cnt[NN] | row_start[NN] | wpos[NN] | total[1]+pad | bucket[NE] | dinv[NN] | g[NN*D]
    int* cnt       = (int*)d_ws;
    int* row_start = cnt + NN;
    int* wpos      = row_start + NN;
    int* total     = wpos + NN;
    int* bucket    = total + 4;           // 16B-align next region
    float* dinv    = (float*)(bucket + NE);
    float* g       = dinv + NN;

    hipLaunchKernelGGL(k_zero,  dim3((NN + 255) / 256), dim3(256), 0, stream, cnt, total);
    hipLaunchKernelGGL(k_count, dim3((NE + 255) / 256), dim3(256), 0, stream, dst, cnt);
    hipLaunchKernelGGL(k_alloc, dim3((NN + 255) / 256), dim3(256), 0, stream,
                       cnt, dinv, row_start, wpos, total);
    hipLaunchKernelGGL(k_gemm,  dim3((NN + 15) / 16), dim3(256), 0, stream,
                       x, pos, Wg, bg, Wp, bp, dinv, g, out);
    hipLaunchKernelGGL(k_fill,  dim3((NE + 255) / 256), dim3(256), 0, stream,
                       src, dst, wpos, bucket);
    hipLaunchKernelGGL(k_gather, dim3((NN + 3) / 4), dim3(256), 0, stream,
                       row_start, cnt, bucket, dinv, g, out);
}

// Round 3
// 469.118 us; speedup vs baseline: 1.7870x; 1.2213x over previous
//
#include <hip/hip_runtime.h>

#define NN 100000
#define NE 1600000
#define D  64

// ---------------- CSR build ----------------
__global__ void k_zero(int* __restrict__ cnt, int* __restrict__ total) {
    int i = blockIdx.x * blockDim.x + threadIdx.x;
    if (i < NN) cnt[i] = 0;
    if (i == 0) *total = 0;
}

__global__ void k_count(const int* __restrict__ dst, int* __restrict__ cnt) {
    int e = blockIdx.x * blockDim.x + threadIdx.x;
    if (e < NE) atomicAdd(&cnt[dst[e]], 1);
}

__global__ __launch_bounds__(256) void k_alloc(
    const int* __restrict__ cnt, float* __restrict__ dinv,
    int* __restrict__ row_start, int* __restrict__ wpos, int* __restrict__ total)
{
    __shared__ int s[256];
    __shared__ int sbase;
    int t = threadIdx.x;
    int i = blockIdx.x * 256 + t;
    int c = (i < NN) ? cnt[i] : 0;
    s[t] = c;
    __syncthreads();
    for (int off = 1; off < 256; off <<= 1) {
        int v = s[t];
        int u = (t >= off) ? s[t - off] : 0;
        __syncthreads();
        s[t] = v + u;
        __syncthreads();
    }
    if (t == 255) sbase = atomicAdd(total, s[255]);
    __syncthreads();
    if (i < NN) {
        int rs = sbase + s[t] - c;
        row_start[i] = rs;
        wpos[i] = rs;
        dinv[i] = rsqrtf((float)(c + 1));   // +1: self-loop
    }
}

__global__ void k_fill(const int* __restrict__ src, const int* __restrict__ dst,
                       int* __restrict__ wpos, int* __restrict__ bucket) {
    int e = blockIdx.x * blockDim.x + threadIdx.x;
    if (e < NE) {
        int d = dst[e];
        int p = atomicAdd(&wpos[d], 1);
        bucket[p] = src[e];
    }
}

// ---------------- GEMM pass 1: g = (x @ Wg) * dinv ----------------
// Lane j holds column j of Wg in 64 VGPRs (loaded once, reused across the
// grid-stride node loop). Node index is wave-uniform (readfirstlane), so the
// x-row loads are uniform float4 broadcasts (scalar path) and every fma is
// v_fma with one SGPR operand. No LDS traffic at all.
__global__ __launch_bounds__(256) void k_mm1(
    const float* __restrict__ x, const float* __restrict__ Wg,
    const float* __restrict__ dinv, float* __restrict__ g)
{
    int lane = threadIdx.x & 63;
    int wid = blockIdx.x * 4 + (threadIdx.x >> 6);
    int nwaves = gridDim.x * 4;

    float w[D];
#pragma unroll
    for (int k = 0; k < D; ++k) w[k] = Wg[k * D + lane];

    for (int n0 = wid; n0 < NN; n0 += nwaves) {
        int n = __builtin_amdgcn_readfirstlane(n0);
        const float4* xr = (const float4*)(x + (long)n * D);
        float acc = 0.f;
#pragma unroll
        for (int k4 = 0; k4 < D / 4; ++k4) {
            float4 v = xr[k4];
            acc = fmaf(v.x, w[4 * k4 + 0], acc);
            acc = fmaf(v.y, w[4 * k4 + 1], acc);
            acc = fmaf(v.z, w[4 * k4 + 2], acc);
            acc = fmaf(v.w, w[4 * k4 + 3], acc);
        }
        g[(long)n * D + lane] = acc * dinv[n];
    }
}

// ---------------- GEMM pass 2: out = pos @ Wp + bg + bp ----------------
__global__ __launch_bounds__(256) void k_mm2(
    const float* __restrict__ pos, const float* __restrict__ Wp,
    const float* __restrict__ bg, const float* __restrict__ bp,
    float* __restrict__ out)
{
    int lane = threadIdx.x & 63;
    int wid = blockIdx.x * 4 + (threadIdx.x >> 6);
    int nwaves = gridDim.x * 4;

    float w[D];
#pragma unroll
    for (int k = 0; k < D; ++k) w[k] = Wp[k * D + lane];
    float bsum = bg[lane] + bp[lane];

    for (int n0 = wid; n0 < NN; n0 += nwaves) {
        int n = __builtin_amdgcn_readfirstlane(n0);
        const float4* pr = (const float4*)(pos + (long)n * D);
        float acc = 0.f;
#pragma unroll
        for (int k4 = 0; k4 < D / 4; ++k4) {
            float4 v = pr[k4];
            acc = fmaf(v.x, w[4 * k4 + 0], acc);
            acc = fmaf(v.y, w[4 * k4 + 1], acc);
            acc = fmaf(v.z, w[4 * k4 + 2], acc);
            acc = fmaf(v.w, w[4 * k4 + 3], acc);
        }
        out[(long)n * D + lane] = acc + bsum;
    }
}

// ---------------- gather (no atomics, no bpermute) ----------------
// Wave per dst node; bucket base/count are wave-uniform, so bucket index
// reads are scalar loads and each neighbor row load has a uniform base.
__global__ __launch_bounds__(256) void k_gather(
    const int* __restrict__ row_start, const int* __restrict__ cnt,
    const int* __restrict__ bucket, const float* __restrict__ dinv,
    const float* __restrict__ g, float* __restrict__ out)
{
    int lane = threadIdx.x & 63;
    int wid = (blockIdx.x << 2) + (threadIdx.x >> 6);
    if (wid >= NN) return;
    int w = __builtin_amdgcn_readfirstlane(wid);

    float acc = g[(long)w * D + lane];   // self-loop term
    int rs = __builtin_amdgcn_readfirstlane(row_start[w]);
    int n  = __builtin_amdgcn_readfirstlane(cnt[w]);
    for (int e = 0; e < n; ++e) {
        int s = __builtin_amdgcn_readfirstlane(bucket[rs + e]);
        acc += g[(long)s * D + lane];
    }
    out[(long)w * D + lane] += acc * dinv[w];
}

extern "C" void kernel_launch(void* const* d_in, const int* in_sizes, int n_in,
                              void* d_out, int out_size, void* d_ws, size_t ws_size,
                              hipStream_t stream) {
    const float* x   = (const float*)d_in[0];
    const int*   ei  = (const int*)d_in[1];   // [2, NE] int32
    const float* pos = (const float*)d_in[2];
    const float* Wg  = (const float*)d_in[3];
    const float* bg  = (const float*)d_in[4];
    const float* Wp  = (const float*)d_in[5];
    const float* bp  = (const float*)d_in[6];
    float* out = (float*)d_out;

    const int* src = ei;
    const int* dst = ei + NE;

    // ws layout: cnt[NN] | row_start[NN] | wpos[NN] | total[1]+pad | bucket[NE] | dinv[NN] | g[NN*D]
    int* cnt       = (int*)d_ws;
    int* row_start = cnt + NN;
    int* wpos      = row_start + NN;
    int* total     = wpos + NN;
    int* bucket    = total + 4;
    float* dinv    = (float*)(bucket + NE);
    float* g       = dinv + NN;

    hipLaunchKernelGGL(k_zero,  dim3((NN + 255) / 256), dim3(256), 0, stream, cnt, total);
    hipLaunchKernelGGL(k_count, dim3((NE + 255) / 256), dim3(256), 0, stream, dst, cnt);
    hipLaunchKernelGGL(k_alloc, dim3((NN + 255) / 256), dim3(256), 0, stream,
                       cnt, dinv, row_start, wpos, total);
    hipLaunchKernelGGL(k_mm1,   dim3(512), dim3(256), 0, stream, x, Wg, dinv, g);
    hipLaunchKernelGGL(k_mm2,   dim3(512), dim3(256), 0, stream, pos, Wp, bg, bp, out);
    hipLaunchKernelGGL(k_fill,  dim3((NE + 255) / 256), dim3(256), 0, stream,
                       src, dst, wpos, bucket);
    hipLaunchKernelGGL(k_gather, dim3((NN + 3) / 4), dim3(256), 0, stream,
                       row_start, cnt, bucket, dinv, g, out);
}

// Round 4
// 403.667 us; speedup vs baseline: 2.0767x; 1.1621x over previous
//
#include <hip/hip_runtime.h>
#include <hip/hip_fp16.h>

#define NN 100000
#define NE 1600000
#define D  64
#define NBLK 391            // ceil(NN/256)
#define RANGES 4
#define RNG 25000           // NN / RANGES

// ---------------- CSR build: count ----------------
__global__ void k_zero(int* __restrict__ cnt) {
    int i = blockIdx.x * blockDim.x + threadIdx.x;
    if (i < NN) cnt[i] = 0;
}

__global__ void k_count(const int* __restrict__ dst, int* __restrict__ cnt) {
    int tid = blockIdx.x * blockDim.x + threadIdx.x;
    int stride = gridDim.x * blockDim.x;
    for (int e = tid; e < NE; e += stride)
        atomicAdd(&cnt[dst[e]], 1);
}

// ---------------- ordered global exclusive scan of cnt ----------------
// A: per-block scan (writes block-local exclusive prefix + block sum)
__global__ __launch_bounds__(256) void k_scanA(
    const int* __restrict__ cnt, int* __restrict__ row_start, int* __restrict__ blockSums)
{
    __shared__ int s[256];
    int t = threadIdx.x;
    int i = blockIdx.x * 256 + t;
    int c = (i < NN) ? cnt[i] : 0;
    s[t] = c;
    __syncthreads();
    for (int off = 1; off < 256; off <<= 1) {
        int add = (t >= off) ? s[t - off] : 0;
        __syncthreads();
        s[t] += add;
        __syncthreads();
    }
    if (i < NN) row_start[i] = s[t] - c;       // block-local exclusive
    if (t == 255) blockSums[blockIdx.x] = s[255];
}

// B: scan the 391 block sums (single block)
__global__ __launch_bounds__(512) void k_scanB(
    const int* __restrict__ blockSums, int* __restrict__ blockBase)
{
    __shared__ int s[512];
    int t = threadIdx.x;
    int v = (t < NBLK) ? blockSums[t] : 0;
    s[t] = v;
    __syncthreads();
    for (int off = 1; off < 512; off <<= 1) {
        int add = (t >= off) ? s[t - off] : 0;
        __syncthreads();
        s[t] += add;
        __syncthreads();
    }
    if (t < NBLK) blockBase[t] = s[t] - v;     // exclusive base per block
}

// C: add base; init wpos, dinv
__global__ __launch_bounds__(256) void k_scanC(
    const int* __restrict__ cnt, const int* __restrict__ blockBase,
    int* __restrict__ row_start, int* __restrict__ wpos, float* __restrict__ dinv)
{
    int i = blockIdx.x * 256 + threadIdx.x;
    if (i >= NN) return;
    int rs = row_start[i] + blockBase[blockIdx.x];
    row_start[i] = rs;
    wpos[i] = rs;
    dinv[i] = rsqrtf((float)(cnt[i] + 1));     // +1: self-loop
}

// ---------------- fill, restricted to a dst range ----------------
// row_start is node-ordered, so a dst range maps to a contiguous ~1.6MB
// bucket slice -> stays L2-resident -> lines fill before eviction (kills the
// 105MB partial-line write-through seen in R3).
__global__ void k_fill_pass(const int* __restrict__ src, const int* __restrict__ dst,
                            int* __restrict__ wpos, int* __restrict__ bucket,
                            int lo, int hi)
{
    int tid = blockIdx.x * blockDim.x + threadIdx.x;
    int stride = gridDim.x * blockDim.x;
    for (int e = tid; e < NE; e += stride) {
        int d = dst[e];
        if (d >= lo && d < hi) {
            int p = atomicAdd(&wpos[d], 1);
            bucket[p] = src[e];
        }
    }
}

// ---------------- GEMM 1: g = half(x @ Wg * dinv) ----------------
__global__ __launch_bounds__(256) void k_mm1(
    const float* __restrict__ x, const float* __restrict__ Wg,
    const float* __restrict__ dinv, __half* __restrict__ g)
{
    int lane = threadIdx.x & 63;
    int wid = blockIdx.x * 4 + (threadIdx.x >> 6);
    int nwaves = gridDim.x * 4;

    float w[D];
#pragma unroll
    for (int k = 0; k < D; ++k) w[k] = Wg[k * D + lane];

    for (int n0 = wid; n0 < NN; n0 += nwaves) {
        int n = __builtin_amdgcn_readfirstlane(n0);
        const float4* xr = (const float4*)(x + (long)n * D);
        float acc = 0.f;
#pragma unroll
        for (int k4 = 0; k4 < D / 4; ++k4) {
            float4 v = xr[k4];
            acc = fmaf(v.x, w[4 * k4 + 0], acc);
            acc = fmaf(v.y, w[4 * k4 + 1], acc);
            acc = fmaf(v.z, w[4 * k4 + 2], acc);
            acc = fmaf(v.w, w[4 * k4 + 3], acc);
        }
        g[(long)n * D + lane] = __float2half(acc * dinv[n]);
    }
}

// ---------------- GEMM 2: out = pos @ Wp + bg + bp ----------------
__global__ __launch_bounds__(256) void k_mm2(
    const float* __restrict__ pos, const float* __restrict__ Wp,
    const float* __restrict__ bg, const float* __restrict__ bp,
    float* __restrict__ out)
{
    int lane = threadIdx.x & 63;
    int wid = blockIdx.x * 4 + (threadIdx.x >> 6);
    int nwaves = gridDim.x * 4;

    float w[D];
#pragma unroll
    for (int k = 0; k < D; ++k) w[k] = Wp[k * D + lane];
    float bsum = bg[lane] + bp[lane];

    for (int n0 = wid; n0 < NN; n0 += nwaves) {
        int n = __builtin_amdgcn_readfirstlane(n0);
        const float4* pr = (const float4*)(pos + (long)n * D);
        float acc = 0.f;
#pragma unroll
        for (int k4 = 0; k4 < D / 4; ++k4) {
            float4 v = pr[k4];
            acc = fmaf(v.x, w[4 * k4 + 0], acc);
            acc = fmaf(v.y, w[4 * k4 + 1], acc);
            acc = fmaf(v.z, w[4 * k4 + 2], acc);
            acc = fmaf(v.w, w[4 * k4 + 3], acc);
        }
        out[(long)n * D + lane] = acc + bsum;
    }
}

// ---------------- gather: wave per node, 4 edge streams ----------------
// Quarter q (16 lanes) holds half4 of the row (features 4f..4f+3) and walks
// edges rs+q, rs+q+4, ... -> 4 independent latency chains per wave. Cross-
// quarter reduce via shfl_xor, then q0 adds self term and writes out.
__device__ __forceinline__ float4 h4_to_f4(uint2 u) {
    __half2 a = *(__half2*)&u.x;
    __half2 b = *(__half2*)&u.y;
    float4 r;
    r.x = __low2float(a); r.y = __high2float(a);
    r.z = __low2float(b); r.w = __high2float(b);
    return r;
}

__global__ __launch_bounds__(256) void k_gather(
    const int* __restrict__ row_start, const int* __restrict__ cnt,
    const int* __restrict__ bucket, const float* __restrict__ dinv,
    const __half* __restrict__ g, float* __restrict__ out)
{
    int lane = threadIdx.x & 63;
    int node = (blockIdx.x << 2) + (threadIdx.x >> 6);
    if (node >= NN) return;
    int q = lane >> 4;
    int f = lane & 15;

    int rs = row_start[node];
    int n  = cnt[node];
    const uint2* gb = (const uint2*)g;   // 8B = half4 granules; row = 16 granules

    float4 acc = make_float4(0.f, 0.f, 0.f, 0.f);
    for (int e = rs + q; e < rs + n; e += 4) {
        int s = bucket[e];
        float4 v = h4_to_f4(gb[((long)s << 4) + f]);
        acc.x += v.x; acc.y += v.y; acc.z += v.z; acc.w += v.w;
    }
    // reduce across the 4 quarters (lanes differing in bits 4,5)
#pragma unroll
    for (int mask = 16; mask <= 32; mask <<= 1) {
        acc.x += __shfl_xor(acc.x, mask);
        acc.y += __shfl_xor(acc.y, mask);
        acc.z += __shfl_xor(acc.z, mask);
        acc.w += __shfl_xor(acc.w, mask);
    }
    if (q == 0) {
        float4 self = h4_to_f4(gb[((long)node << 4) + f]);
        float di = dinv[node];
        float4* op = (float4*)(out + (long)node * D) + f;
        float4 o = *op;
        o.x += (acc.x + self.x) * di;
        o.y += (acc.y + self.y) * di;
        o.z += (acc.z + self.z) * di;
        o.w += (acc.w + self.w) * di;
        *op = o;
    }
}

extern "C" void kernel_launch(void* const* d_in, const int* in_sizes, int n_in,
                              void* d_out, int out_size, void* d_ws, size_t ws_size,
                              hipStream_t stream) {
    const float* x   = (const float*)d_in[0];
    const int*   ei  = (const int*)d_in[1];   // [2, NE] int32
    const float* pos = (const float*)d_in[2];
    const float* Wg  = (const float*)d_in[3];
    const float* bg  = (const float*)d_in[4];
    const float* Wp  = (const float*)d_in[5];
    const float* bp  = (const float*)d_in[6];
    float* out = (float*)d_out;

    const int* src = ei;
    const int* dst = ei + NE;

    // ws layout: cnt[NN] | row_start[NN] | wpos[NN] | blockSums[512] | blockBase[512]
    //            | bucket[NE] | dinv[NN] | g_half[NN*D]
    int* cnt       = (int*)d_ws;
    int* row_start = cnt + NN;
    int* wpos      = row_start + NN;
    int* blockSums = wpos + NN;
    int* blockBase = blockSums + 512;
    int* bucket    = blockBase + 512;
    float* dinv    = (float*)(bucket + NE);
    __half* g      = (__half*)(dinv + NN);

    hipLaunchKernelGGL(k_zero,  dim3(NBLK), dim3(256), 0, stream, cnt);
    hipLaunchKernelGGL(k_count, dim3(1024), dim3(256), 0, stream, dst, cnt);
    hipLaunchKernelGGL(k_scanA, dim3(NBLK), dim3(256), 0, stream, cnt, row_start, blockSums);
    hipLaunchKernelGGL(k_scanB, dim3(1),    dim3(512), 0, stream, blockSums, blockBase);
    hipLaunchKernelGGL(k_scanC, dim3(NBLK), dim3(256), 0, stream, cnt, blockBase, row_start, wpos, dinv);
    hipLaunchKernelGGL(k_mm1,   dim3(512),  dim3(256), 0, stream, x, Wg, dinv, g);
    hipLaunchKernelGGL(k_mm2,   dim3(512),  dim3(256), 0, stream, pos, Wp, bg, bp, out);
    for (int p = 0; p < RANGES; ++p)
        hipLaunchKernelGGL(k_fill_pass, dim3(1024), dim3(256), 0, stream,
                           src, dst, wpos, bucket, p * RNG, (p + 1) * RNG);
    hipLaunchKernelGGL(k_gather, dim3((NN + 3) / 4), dim3(256), 0, stream,
                       row_start, cnt, bucket, dinv, g, out);
}

// Round 6
// 316.579 us; speedup vs baseline: 2.6480x; 1.2751x over previous
//
#include <hip/hip_runtime.h>
#include <hip/hip_fp16.h>

#define NN 100000
#define NE 1600000
#define D  64

#define B1    256          // phase-1 blocks
#define CHUNK 6250         // NE / B1
#define BSH   9            // coarse bin = dst >> 9  (512 nodes per bin)
#define BMSK  511
#define NB    196          // ceil(NN / 512)
#define M     (NB * B1)    // hist entries = 50176 = 1024 * 49

// ---------- phase A: per-block coarse histogram (LDS atomics only) ----------
__global__ __launch_bounds__(256) void k_hist(const int* __restrict__ dst,
                                              int* __restrict__ hist) {
    __shared__ int h[NB];
    int t = threadIdx.x, blk = blockIdx.x;
    for (int i = t; i < NB; i += 256) h[i] = 0;
    __syncthreads();
    int e0 = blk * CHUNK;
    for (int e = e0 + t; e < e0 + CHUNK; e += 256)
        atomicAdd(&h[dst[e] >> BSH], 1);
    __syncthreads();
    for (int i = t; i < NB; i += 256) hist[i * B1 + blk] = h[i];  // bin-major
}

// ---------- exclusive scan of the 50176-entry (bin-major) matrix ----------
__global__ __launch_bounds__(1024) void k_scan(int* __restrict__ hist) {
    __shared__ int ps[1024];
    int t = threadIdx.x;
    const int C = M / 1024;          // 49
    int base = t * C;
    int s = 0;
    for (int i = 0; i < C; ++i) s += hist[base + i];
    ps[t] = s;
    __syncthreads();
    for (int off = 1; off < 1024; off <<= 1) {
        int u = (t >= off) ? ps[t - off] : 0;
        __syncthreads();
        ps[t] += u;
        __syncthreads();
    }
    int run = ps[t] - s;             // exclusive prefix of this chunk
    for (int i = 0; i < C; ++i) { int c = hist[base + i]; hist[base + i] = run; run += c; }
}

// ---------- phase B: scatter packed (src<<9 | local) into bin-contig ebuf ----------
__global__ __launch_bounds__(256) void k_scatter1(
    const int* __restrict__ src, const int* __restrict__ dst,
    const int* __restrict__ hist, unsigned* __restrict__ ebuf)
{
    __shared__ int cur[NB];
    int t = threadIdx.x, blk = blockIdx.x;
    for (int i = t; i < NB; i += 256) cur[i] = hist[i * B1 + blk];
    __syncthreads();
    int e0 = blk * CHUNK;
    for (int e = e0 + t; e < e0 + CHUNK; e += 256) {
        int d = dst[e];
        int p = atomicAdd(&cur[d >> BSH], 1);            // LDS atomic
        ebuf[p] = ((unsigned)src[e] << BSH) | (unsigned)(d & BMSK);
    }
}

// ---------- phase C: per-bin exact CSR, all in LDS ----------
__global__ __launch_bounds__(256) void k_build(
    const int* __restrict__ hist, const unsigned* __restrict__ ebuf,
    int* __restrict__ rs, float* __restrict__ dinv, int* __restrict__ bucket)
{
    __shared__ int c[512];
    __shared__ int ps[256];
    int t = threadIdx.x, b = blockIdx.x;
    int e0 = hist[b * B1];
    int e1 = (b == NB - 1) ? NE : hist[(b + 1) * B1];
    c[t] = 0; c[t + 256] = 0;
    __syncthreads();
    for (int e = e0 + t; e < e1; e += 256)
        atomicAdd(&c[ebuf[e] & BMSK], 1);
    __syncthreads();
    int a = c[2 * t], d2 = c[2 * t + 1];
    ps[t] = a + d2;
    __syncthreads();
    for (int off = 1; off < 256; off <<= 1) {
        int u = (t >= off) ? ps[t - off] : 0;
        __syncthreads();
        ps[t] += u;
        __syncthreads();
    }
    int ex = ps[t] - (a + d2);       // exclusive over pairs
    int p0 = e0 + ex, p1 = e0 + ex + a;
    int node0 = (b << BSH) + 2 * t, node1 = node0 + 1;
    if (node0 < NN) { rs[node0] = p0; dinv[node0] = rsqrtf((float)(a + 1)); }
    if (node1 < NN) { rs[node1] = p1; dinv[node1] = rsqrtf((float)(d2 + 1)); }
    if (b == NB - 1 && t == 0) rs[NN] = NE;
    __syncthreads();                 // all reads of c done (barrier-separated above)
    c[2 * t] = p0; c[2 * t + 1] = p1;  // cursors
    __syncthreads();
    for (int e = e0 + t; e < e1; e += 256) {
        unsigned u = ebuf[e];
        int p = atomicAdd(&c[u & BMSK], 1);              // LDS atomic
        bucket[p] = (int)(u >> BSH);
    }
}

// ---------- GEMM 1: g = half(x @ Wg * dinv) ----------
__global__ __launch_bounds__(256) void k_mm1(
    const float* __restrict__ x, const float* __restrict__ Wg,
    const float* __restrict__ dinv, __half* __restrict__ g)
{
    int lane = threadIdx.x & 63;
    int wid = blockIdx.x * 4 + (threadIdx.x >> 6);
    int nwaves = gridDim.x * 4;
    float w[D];
#pragma unroll
    for (int k = 0; k < D; ++k) w[k] = Wg[k * D + lane];
    for (int n0 = wid; n0 < NN; n0 += nwaves) {
        int n = __builtin_amdgcn_readfirstlane(n0);
        const float4* xr = (const float4*)(x + (long)n * D);
        float acc = 0.f;
#pragma unroll
        for (int k4 = 0; k4 < D / 4; ++k4) {
            float4 v = xr[k4];
            acc = fmaf(v.x, w[4 * k4 + 0], acc);
            acc = fmaf(v.y, w[4 * k4 + 1], acc);
            acc = fmaf(v.z, w[4 * k4 + 2], acc);
            acc = fmaf(v.w, w[4 * k4 + 3], acc);
        }
        g[(long)n * D + lane] = __float2half(acc * dinv[n]);
    }
}

// ---------- GEMM 2: out = pos @ Wp + bg + bp ----------
__global__ __launch_bounds__(256) void k_mm2(
    const float* __restrict__ pos, const float* __restrict__ Wp,
    const float* __restrict__ bg, const float* __restrict__ bp,
    float* __restrict__ out)
{
    int lane = threadIdx.x & 63;
    int wid = blockIdx.x * 4 + (threadIdx.x >> 6);
    int nwaves = gridDim.x * 4;
    float w[D];
#pragma unroll
    for (int k = 0; k < D; ++k) w[k] = Wp[k * D + lane];
    float bsum = bg[lane] + bp[lane];
    for (int n0 = wid; n0 < NN; n0 += nwaves) {
        int n = __builtin_amdgcn_readfirstlane(n0);
        const float4* pr = (const float4*)(pos + (long)n * D);
        float acc = 0.f;
#pragma unroll
        for (int k4 = 0; k4 < D / 4; ++k4) {
            float4 v = pr[k4];
            acc = fmaf(v.x, w[4 * k4 + 0], acc);
            acc = fmaf(v.y, w[4 * k4 + 1], acc);
            acc = fmaf(v.z, w[4 * k4 + 2], acc);
            acc = fmaf(v.w, w[4 * k4 + 3], acc);
        }
        out[(long)n * D + lane] = acc + bsum;
    }
}

// ---------- gather: wave per node, 4 edge streams ----------
__device__ __forceinline__ float4 h4_to_f4(uint2 u) {
    __half2 a = *(__half2*)&u.x;
    __half2 b = *(__half2*)&u.y;
    float4 r;
    r.x = __low2float(a); r.y = __high2float(a);
    r.z = __low2float(b); r.w = __high2float(b);
    return r;
}

__global__ __launch_bounds__(256) void k_gather(
    const int* __restrict__ rs, const int* __restrict__ bucket,
    const float* __restrict__ dinv, const __half* __restrict__ g,
    float* __restrict__ out)
{
    int lane = threadIdx.x & 63;
    int node = (blockIdx.x << 2) + (threadIdx.x >> 6);
    if (node >= NN) return;
    int q = lane >> 4;
    int f = lane & 15;
    int r0 = rs[node], r1 = rs[node + 1];
    const uint2* gb = (const uint2*)g;          // 8B half4 granules; row = 16

    float4 acc = make_float4(0.f, 0.f, 0.f, 0.f);
    for (int e = r0 + q; e < r1; e += 4) {
        int s = bucket[e];
        float4 v = h4_to_f4(gb[((long)s << 4) + f]);
        acc.x += v.x; acc.y += v.y; acc.z += v.z; acc.w += v.w;
    }
#pragma unroll
    for (int mask = 16; mask <= 32; mask <<= 1) {
        acc.x += __shfl_xor(acc.x, mask);
        acc.y += __shfl_xor(acc.y, mask);
        acc.z += __shfl_xor(acc.z, mask);
        acc.w += __shfl_xor(acc.w, mask);
    }
    if (q == 0) {
        float4 self = h4_to_f4(gb[((long)node << 4) + f]);
        float di = dinv[node];
        float4* op = (float4*)(out + (long)node * D) + f;
        float4 o = *op;
        o.x += (acc.x + self.x) * di;
        o.y += (acc.y + self.y) * di;
        o.z += (acc.z + self.z) * di;
        o.w += (acc.w + self.w) * di;
        *op = o;
    }
}

extern "C" void kernel_launch(void* const* d_in, const int* in_sizes, int n_in,
                              void* d_out, int out_size, void* d_ws, size_t ws_size,
                              hipStream_t stream) {
    const float* x   = (const float*)d_in[0];
    const int*   ei  = (const int*)d_in[1];   // [2, NE] int32
    const float* pos = (const float*)d_in[2];
    const float* Wg  = (const float*)d_in[3];
    const float* bg  = (const float*)d_in[4];
    const float* Wp  = (const float*)d_in[5];
    const float* bp  = (const float*)d_in[6];
    float* out = (float*)d_out;

    const int* src = ei;
    const int* dst = ei + NE;

    // ws: hist[M] | ebuf[NE] u32 | bucket[NE] | rs[NN+4] | dinv[NN] | g[NN*D] half
    // (~26.6 MB; offsets keep g 8B-aligned for uint2 loads)
    int*      hist   = (int*)d_ws;
    unsigned* ebuf   = (unsigned*)(hist + M);
    int*      bucket = (int*)(ebuf + NE);
    int*      rs     = bucket + NE;
    float*    dinv   = (float*)(rs + NN + 4);
    __half*   g      = (__half*)(dinv + NN);

    hipLaunchKernelGGL(k_hist,     dim3(B1),  dim3(256),  0, stream, dst, hist);
    hipLaunchKernelGGL(k_scan,     dim3(1),   dim3(1024), 0, stream, hist);
    hipLaunchKernelGGL(k_scatter1, dim3(B1),  dim3(256),  0, stream, src, dst, hist, ebuf);
    hipLaunchKernelGGL(k_build,    dim3(NB),  dim3(256),  0, stream, hist, ebuf, rs, dinv, bucket);
    hipLaunchKernelGGL(k_mm1,      dim3(512), dim3(256),  0, stream, x, Wg, dinv, g);
    hipLaunchKernelGGL(k_mm2,      dim3(512), dim3(256),  0, stream, pos, Wp, bg, bp, out);
    hipLaunchKernelGGL(k_gather,   dim3((NN + 3) / 4), dim3(256), 0, stream,
                       rs, bucket, dinv, g, out);
}